// Round 5
// baseline (549.975 us; speedup 1.0000x reference)
//
#include <hip/hip_runtime.h>
#include <math.h>

#define LL 4
#define NN 40000
#define DD 128
#define EE 320000
#define ROWS (LL*NN)         // 160000
#define ND (NN*DD)           // 5120000
#define EPS_LN 1e-5f

typedef __attribute__((ext_vector_type(8))) short bf16x8;
typedef __attribute__((ext_vector_type(4))) short s16x4;
typedef __attribute__((ext_vector_type(4))) float f32x4;

// ---------------- workspace layout (units of 4 bytes) ----------------
#define OFF_CNT      0                         // NN ints
#define OFF_ROWPTR   40000                     // NN+1
#define OFF_ROWOFS   80004                     // NN
#define OFF_CCOLS    120004                    // EE
#define OFF_CVALS    440004                    // EE
#define OFF_WBF      760004                    // bf16 hi/lo weights (139264 shorts)
#define OFF_A        829636                    // bf16 A [N][L][D]: ROWS*DD shorts
#define OFF_B        (OFF_A + ROWS*DD/2)       // bf16 B [N][L][D]
#define OFF_XBF      (OFF_B + ROWS*DD/2)       // bf16 x [N][L][D] for spmm pass 1
// scan scratch aliases the A region (dead until spmm1, which runs after scan3)

// weight sub-offsets in SHORTS within WBF region. Each big matrix: 16384 hi then 16384 lo.
#define WB_W0  0        // sage_W^T      [n][k] 128x128
#define WB_W1  32768    // sage_agg_W^T
#define WB_WV  65536    // value_W^T
#define WB_WL  98304    // lin_W^T
#define WB_K   131072   // key_W^T   [16][128]: 2048 hi then 2048 lo
#define WB_Q   135168   // query_W^T
#define WB_LO_BIG 16384
#define WB_LO_KQ  2048
#define WB_LOGICAL 69632

__device__ __forceinline__ unsigned fu(float f) { union { float f; unsigned u; } v; v.f = f; return v.u; }
__device__ __forceinline__ float uf(unsigned u) { union { unsigned u; float f; } v; v.u = u; return v.f; }

__device__ __forceinline__ short f2bf(float f) {           // RNE
    unsigned u = fu(f);
    unsigned r = u + 0x7fffu + ((u >> 16) & 1u);
    return (short)(r >> 16);
}
__device__ __forceinline__ float bf2f(short h) { return uf(((unsigned)(unsigned short)h) << 16); }
__device__ __forceinline__ void splitbf(float v, short& h, short& l) {  // prep only
    h = f2bf(v);
    l = f2bf(v - bf2f(h));
}

// truncation pack: two floats -> one VGPR of 2 bf16 (lo short = a, hi short = b)
__device__ __forceinline__ unsigned pack_hi(float a, float b) {
    return (fu(a) >> 16) | (fu(b) & 0xffff0000u);
}
// truncation residual
__device__ __forceinline__ float resid(float a) {
    return a - uf(fu(a) & 0xffff0000u);
}

union FragU { bf16x8 v; unsigned u[4]; };

// ---------------- CSR build ----------------
__global__ void k_hist(const int* __restrict__ rows, int* __restrict__ cnt) {
    int e = blockIdx.x * 256 + threadIdx.x;
    if (e < EE) atomicAdd(&cnt[rows[e]], 1);
}

// hierarchical scan: scan1 (40 blocks local excl-scan) -> scan2 (scan 40 totals) -> scan3 (add offsets)
__global__ __launch_bounds__(1024) void k_scan1(const int* __restrict__ cnt,
                                                int* __restrict__ row_ptr,
                                                int* __restrict__ bsum) {
    __shared__ int wtot[16];
    int tid = threadIdx.x, lane = tid & 63, wid = tid >> 6;
    int i = blockIdx.x * 1024 + tid;
    int v = (i < NN) ? cnt[i] : 0;
    int incl = v;
    #pragma unroll
    for (int off = 1; off < 64; off <<= 1) {
        int t = __shfl_up(incl, off);
        if (lane >= off) incl += t;
    }
    if (lane == 63) wtot[wid] = incl;
    __syncthreads();
    if (wid == 0) {
        int wv = (lane < 16) ? wtot[lane] : 0;
        #pragma unroll
        for (int off = 1; off < 16; off <<= 1) {
            int t = __shfl_up(wv, off);
            if (lane >= off) wv += t;
        }
        if (lane < 16) wtot[lane] = wv;
    }
    __syncthreads();
    int excl = ((wid > 0) ? wtot[wid - 1] : 0) + incl - v;
    if (i < NN) row_ptr[i] = excl;            // local exclusive; global offset added in scan3
    if (tid == 0) bsum[blockIdx.x] = wtot[15];
}

__global__ void k_scan2(const int* __restrict__ bsum, int* __restrict__ bofs) {
    int lane = threadIdx.x;                   // 64 threads, 1 block
    int v = (lane < 40) ? bsum[lane] : 0;
    int incl = v;
    #pragma unroll
    for (int off = 1; off < 64; off <<= 1) {
        int t = __shfl_up(incl, off);
        if (lane >= off) incl += t;
    }
    if (lane < 40) bofs[lane] = incl - v;
    if (lane == 39) bofs[40] = incl;          // grand total
}

__global__ __launch_bounds__(1024) void k_scan3(const int* __restrict__ bofs,
                                                int* __restrict__ row_ptr,
                                                int* __restrict__ row_ofs) {
    int i = blockIdx.x * 1024 + threadIdx.x;
    int add = bofs[blockIdx.x];
    if (i < NN) {
        int v = row_ptr[i] + add;
        row_ptr[i] = v;
        row_ofs[i] = v;
    }
    if (i == NN) row_ptr[NN] = bofs[40];
}

__global__ void k_scatter(const int* __restrict__ rows, const int* __restrict__ cols,
                          const float* __restrict__ vals, int* __restrict__ row_ofs,
                          int* __restrict__ csr_cols, float* __restrict__ csr_vals) {
    int e = blockIdx.x * 256 + threadIdx.x;
    if (e < EE) {
        int r = rows[e];
        int p = atomicAdd(&row_ofs[r], 1);
        csr_cols[p] = cols[e];
        csr_vals[p] = vals[e];
    }
}

// ---------------- x [L][N][D] fp32 -> Xbf [N][L][D] bf16 (node-major for spmm gathers) ----------------
__global__ __launch_bounds__(256) void k_xcast(const float* __restrict__ x, short* __restrict__ o) {
    int t = blockIdx.x * 256 + threadIdx.x;   // 2500 blocks: t in [0, 640000)
    int n = t >> 4;
    int d8 = (t & 15) * 8;
    #pragma unroll
    for (int l = 0; l < LL; ++l) {
        const float* xp = x + (size_t)l * ND + (size_t)n * 128 + d8;
        f32x4 a = *(const f32x4*)xp;
        f32x4 b = *(const f32x4*)(xp + 4);
        bf16x8 r;
        #pragma unroll
        for (int j = 0; j < 4; ++j) { r[j] = f2bf(a[j]); r[j + 4] = f2bf(b[j]); }
        *(bf16x8*)(o + (size_t)n * 512 + l * 128 + d8) = r;
    }
}

// ---------------- SpMM node-major, 2 rows per wave ----------------
// [N][L][D] bf16: each edge's gather is one contiguous 1 KB wave access. Two
// consecutive rows per wave = two independent gather chains interleaved (4+4 deep)
// for 2x memory-level parallelism when latency-bound. 4 waves/block => 8 rows/block.
__global__ __launch_bounds__(256) void k_spmm(const short* __restrict__ in,
                                              const int* __restrict__ row_ptr,
                                              const int* __restrict__ ccols,
                                              const float* __restrict__ cvals,
                                              short* __restrict__ out) {
    int wid = blockIdx.x * 4 + (threadIdx.x >> 6);
    int rA = wid * 2;                        // rows rA, rA+1
    int lane = threadIdx.x & 63;
    const short* inl = in + lane * 8;
    float accA[8] = {0.f,0.f,0.f,0.f,0.f,0.f,0.f,0.f};
    float accB[8] = {0.f,0.f,0.f,0.f,0.f,0.f,0.f,0.f};
    int a0 = row_ptr[rA], a1 = row_ptr[rA + 1], b1 = row_ptr[rA + 2];
    int b0 = a1;
    // joint loop: 4 gathers per row in flight (8 total)
    while (a0 + 4 <= a1 && b0 + 4 <= b1) {
        int ca[4], cb[4]; float va[4], vb[4]; bf16x8 xa[4], xb[4];
        #pragma unroll
        for (int j = 0; j < 4; ++j) {
            ca[j] = ccols[a0 + j]; va[j] = cvals[a0 + j];
            cb[j] = ccols[b0 + j]; vb[j] = cvals[b0 + j];
        }
        #pragma unroll
        for (int j = 0; j < 4; ++j) {
            xa[j] = *(const bf16x8*)(inl + (size_t)ca[j] * 512);
            xb[j] = *(const bf16x8*)(inl + (size_t)cb[j] * 512);
        }
        #pragma unroll
        for (int j = 0; j < 4; ++j)
            #pragma unroll
            for (int k = 0; k < 8; ++k) {
                accA[k] += va[j] * bf2f(xa[j][k]);
                accB[k] += vb[j] * bf2f(xb[j][k]);
            }
        a0 += 4; b0 += 4;
    }
    // per-row tails (4-deep then scalar)
    #pragma unroll 1
    for (int pass = 0; pass < 2; ++pass) {
        int e = pass ? b0 : a0, e1 = pass ? b1 : a1;
        float* acc = pass ? accB : accA;
        for (; e + 4 <= e1; e += 4) {
            int cc[4]; float vv[4]; bf16x8 xv[4];
            #pragma unroll
            for (int j = 0; j < 4; ++j) { cc[j] = ccols[e + j]; vv[j] = cvals[e + j]; }
            #pragma unroll
            for (int j = 0; j < 4; ++j) xv[j] = *(const bf16x8*)(inl + (size_t)cc[j] * 512);
            #pragma unroll
            for (int j = 0; j < 4; ++j)
                #pragma unroll
                for (int k = 0; k < 8; ++k) acc[k] += vv[j] * bf2f(xv[j][k]);
        }
        for (; e < e1; ++e) {
            int c = ccols[e];
            float v = cvals[e];
            bf16x8 xv = *(const bf16x8*)(inl + (size_t)c * 512);
            #pragma unroll
            for (int k = 0; k < 8; ++k) acc[k] += v * bf2f(xv[k]);
        }
    }
    bf16x8 oA, oB;
    #pragma unroll
    for (int k = 0; k < 8; ++k) { oA[k] = f2bf(accA[k]); oB[k] = f2bf(accB[k]); }
    *(bf16x8*)(out + (size_t)rA * 512 + lane * 8) = oA;
    *(bf16x8*)(out + (size_t)(rA + 1) * 512 + lane * 8) = oB;
}

// ---------------- weight prep: fp32 [k][n] -> bf16 hi/lo transposed [n][k] ----------------
__global__ void k_prep(const float* __restrict__ W0, const float* __restrict__ W1,
                       const float* __restrict__ Wv, const float* __restrict__ Wl,
                       const float* __restrict__ Kw, const float* __restrict__ Qw,
                       short* __restrict__ o) {
    int t = blockIdx.x * 256 + threadIdx.x;
    if (t >= WB_LOGICAL) return;
    float v;
    int hi_idx, lo_idx;
    if (t < 65536) {
        int m = t >> 14, idx = t & 16383;
        int nn = idx >> 7, kk = idx & 127;
        const float* M = (m == 0) ? W0 : (m == 1) ? W1 : (m == 2) ? Wv : Wl;
        v = M[kk * 128 + nn];
        hi_idx = m * 32768 + idx;
        lo_idx = hi_idx + WB_LO_BIG;
    } else {
        int t2 = t - 65536;
        int sel = t2 >> 11;
        int idx = t2 & 2047;
        int nn = idx >> 7, kk = idx & 127;
        const float* M = sel ? Qw : Kw;
        v = M[kk * 16 + nn];
        hi_idx = WB_K + sel * 4096 + idx;
        lo_idx = hi_idx + WB_LO_KQ;
    }
    short h, l;
    splitbf(v, h, l);
    o[hi_idx] = h;
    o[lo_idx] = l;
}

// ============ fused dense stage, t-halved phases for accumulator pressure ============
// 2500 blocks x 256 (4 waves); wave w owns rows blk*64 + w*16 .. +16 (full 128 cols).
// MFMA 16x16x32 bf16 (m89-verified):
//   A-frag: lane holds row m=lane&15, k=(lane>>4)*8+j   B-frag: col n=lane&15, same k
//   C/D:    col = lane&15, row = (lane>>4)*4 + reg
// Round-4 post-mortem: occupancy binder is arch+ACC on the unified file (VGPR_Count
// shows arch only). Fix: every 8-wide output phase runs as two sequential 4-wide
// halves (#pragma unroll 1 stops re-merging) -> 16 acc live instead of 32; peak acc
// is now the qk phase's 24. Stage-2 halves spill silu(F) as fp32 into the p/v LDS
// region (dead after zh is built) so the final LN runs after both halves.
#define MFMA(a, b, c) __builtin_amdgcn_mfma_f32_16x16x32_bf16(a, b, c, 0, 0, 0)

__global__ __launch_bounds__(256) void k_dense(
    const float* __restrict__ x, const short* __restrict__ A, const short* __restrict__ B,
    const short* __restrict__ wbf,
    const float* __restrict__ sage_b, const float* __restrict__ attn_g,
    const float* __restrict__ attn_b, const float* __restrict__ lin_b,
    const float* __restrict__ ln_g, const float* __restrict__ ln_b,
    float* __restrict__ out)
{
    __shared__ short pv[4][2][2048];         // [wave][p,v][16x128 bf16, XOR-swizzled]
    const int tid = threadIdx.x;
    const int w = tid >> 6;
    const int lane = tid & 63;
    const int n = lane & 15;
    const int q = lane >> 4;
    const int rowA = blockIdx.x * 64 + w * 16 + n;     // = l*NN + node (blocks never straddle layers)
    const int l = rowA / NN;
    const int node = rowA - l * NN;
    char* pB = (char*)&pv[w][0][0];
    char* vB = (char*)&pv[w][1][0];

    bf16x8 xh[4], ah[4], ch[4];              // persistent frags
    f32x4 kx = {0,0,0,0}, qx = {0,0,0,0};
    f32x4 ka = {0,0,0,0}, qa = {0,0,0,0};
    f32x4 kb = {0,0,0,0}, qb = {0,0,0,0};

    // ---- phase 0: load row data, build frags, qk MFMAs ----
    {
        const float* xp = x + (size_t)rowA * 128 + q * 8;
        const short* ap = A + (size_t)node * 512 + l * 128 + q * 8;   // [N][L][D]
        const short* bp = B + (size_t)node * 512 + l * 128 + q * 8;
        const short* Kp = wbf + WB_K + n * 128 + q * 8;
        const short* Qp = wbf + WB_Q + n * 128 + q * 8;
        #pragma unroll
        for (int s = 0; s < 4; ++s) {
            f32x4 x0 = *(const f32x4*)(xp + s * 32);
            f32x4 x1 = *(const f32x4*)(xp + s * 32 + 4);
            bf16x8 av = *(const bf16x8*)(ap + s * 32);
            bf16x8 bv = *(const bf16x8*)(bp + s * 32);

            f32x4 c0, c1;
            #pragma unroll
            for (int j = 0; j < 4; ++j) {
                c0[j] = x0[j] + 0.5f * bf2f(av[j])     + 0.25f * bf2f(bv[j]);
                c1[j] = x1[j] + 0.5f * bf2f(av[j + 4]) + 0.25f * bf2f(bv[j + 4]);
            }

            FragU fxh, fxl, fch;
            #pragma unroll
            for (int i = 0; i < 2; ++i) {
                fxh.u[i]     = pack_hi(x0[2*i], x0[2*i+1]);
                fxh.u[i + 2] = pack_hi(x1[2*i], x1[2*i+1]);
                fxl.u[i]     = pack_hi(resid(x0[2*i]), resid(x0[2*i+1]));
                fxl.u[i + 2] = pack_hi(resid(x1[2*i]), resid(x1[2*i+1]));
                fch.u[i]     = pack_hi(c0[2*i], c0[2*i+1]);
                fch.u[i + 2] = pack_hi(c1[2*i], c1[2*i+1]);
            }
            xh[s] = fxh.v; ah[s] = av; ch[s] = fch.v;

            bf16x8 bkh = *(const bf16x8*)(Kp + s * 32);
            bf16x8 bkl = *(const bf16x8*)(Kp + WB_LO_KQ + s * 32);
            bf16x8 bqh = *(const bf16x8*)(Qp + s * 32);
            bf16x8 bql = *(const bf16x8*)(Qp + WB_LO_KQ + s * 32);
            // x path: split product hi.hi + lo.hi + hi.lo
            kx = MFMA(fxh.v, bkh, kx); kx = MFMA(fxl.v, bkh, kx); kx = MFMA(fxh.v, bkl, kx);
            qx = MFMA(fxh.v, bqh, qx); qx = MFMA(fxl.v, bqh, qx); qx = MFMA(fxh.v, bql, qx);
            // A/B paths: hi-only (terms carry 0.25 / 0.0625 weight)
            ka = MFMA(av, bkh, ka); qa = MFMA(av, bqh, qa);
            kb = MFMA(bv, bkh, kb); qb = MFMA(bv, bqh, qb);
        }
    }

    // wts = mean(kx*qx) + 0.25*mean(ka*qa) + 0.0625*mean(kb*qb)   (mean over 16 cols)
    f32x4 wts;
    #pragma unroll
    for (int r = 0; r < 4; ++r) {
        float p = kx[r] * qx[r] + 0.25f * (ka[r] * qa[r]) + 0.0625f * (kb[r] * qb[r]);
        p += __shfl_xor(p, 1);
        p += __shfl_xor(p, 2);
        p += __shfl_xor(p, 4);
        p += __shfl_xor(p, 8);
        wts[r] = p * (1.f / 16.f);
    }

    // ---- phase 1: SAGE S = silu(x@W0 + b + A@W1), two 4-col halves, spill to pB ----
    #pragma unroll 1
    for (int h = 0; h < 2; ++h) {
        f32x4 S[4];
        #pragma unroll
        for (int t = 0; t < 4; ++t) {
            float bv = sage_b[(h * 4 + t) * 16 + n];
            S[t] = (f32x4){bv, bv, bv, bv};
        }
        #pragma unroll
        for (int s = 0; s < 4; ++s) {
            #pragma unroll
            for (int t = 0; t < 4; ++t) {
                int col = (h * 4 + t) * 16 + n;
                bf16x8 w0h = *(const bf16x8*)(wbf + WB_W0 + col * 128 + s * 32 + q * 8);
                S[t] = MFMA(xh[s], w0h, S[t]);
                bf16x8 w1h = *(const bf16x8*)(wbf + WB_W1 + col * 128 + s * 32 + q * 8);
                S[t] = MFMA(ah[s], w1h, S[t]);
            }
        }
        #pragma unroll
        for (int t = 0; t < 4; ++t)
            #pragma unroll
            for (int r = 0; r < 4; ++r) {
                float v = S[t][r];
                v = v / (1.f + __expf(-v));
                int row = q * 4 + r;
                int byte = (row * 256 + ((h * 4 + t) * 16 + n) * 2) ^ ((row & 7) << 4);
                *(short*)(pB + byte) = f2bf(v);
            }
    }
    asm volatile("" ::: "memory");

    // ---- phase 2: V = (ch @ Wv) * wts, two halves, LN stats in regs, spill to vB ----
    float mu_n, rs_n;
    {
        f32x4 s1 = {0,0,0,0}, s2 = {0,0,0,0};
        #pragma unroll 1
        for (int h = 0; h < 2; ++h) {
            f32x4 V[4];
            #pragma unroll
            for (int t = 0; t < 4; ++t) V[t] = (f32x4){0.f, 0.f, 0.f, 0.f};
            #pragma unroll
            for (int s = 0; s < 4; ++s)
                #pragma unroll
                for (int t = 0; t < 4; ++t) {
                    int col = (h * 4 + t) * 16 + n;
                    bf16x8 wvh = *(const bf16x8*)(wbf + WB_WV + col * 128 + s * 32 + q * 8);
                    V[t] = MFMA(ch[s], wvh, V[t]);
                }
            #pragma unroll
            for (int t = 0; t < 4; ++t)
                #pragma unroll
                for (int r = 0; r < 4; ++r) {
                    float v = V[t][r] * wts[r];
                    s1[r] += v; s2[r] += v * v;
                    int row = q * 4 + r;
                    int byte = (row * 256 + ((h * 4 + t) * 16 + n) * 2) ^ ((row & 7) << 4);
                    *(short*)(vB + byte) = f2bf(v);
                }
        }
        #pragma unroll
        for (int r = 0; r < 4; ++r) {
            float a1 = s1[r], a2 = s2[r];
            a1 += __shfl_xor(a1, 1); a2 += __shfl_xor(a2, 1);
            a1 += __shfl_xor(a1, 2); a2 += __shfl_xor(a2, 2);
            a1 += __shfl_xor(a1, 4); a2 += __shfl_xor(a2, 4);
            a1 += __shfl_xor(a1, 8); a2 += __shfl_xor(a2, 8);
            s1[r] = a1; s2[r] = a2;
        }
        float mu4[4], rs4[4];
        #pragma unroll
        for (int r = 0; r < 4; ++r) {
            mu4[r] = s1[r] * (1.f / 128.f);
            float var = s2[r] * (1.f / 128.f) - mu4[r] * mu4[r];
            rs4[r] = rsqrtf(var + EPS_LN);
        }
        // broadcast row-stats to transposed lanes: lane (q,n) needs stats of row n,
        // held by lane src = (n>>2)*16 in component n&3.
        int src = (n >> 2) << 4;
        float mA = __shfl(mu4[0], src), mB_ = __shfl(mu4[1], src);
        float mC = __shfl(mu4[2], src), mD = __shfl(mu4[3], src);
        float rA = __shfl(rs4[0], src), rB_ = __shfl(rs4[1], src);
        float rC = __shfl(rs4[2], src), rD = __shfl(rs4[3], src);
        float m01 = (n & 1) ? mB_ : mA, m23 = (n & 1) ? mD : mC;
        float r01 = (n & 1) ? rB_ : rA, r23 = (n & 1) ? rD : rC;
        mu_n = (n & 2) ? m23 : m01;
        rs_n = (n & 2) ? r23 : r01;
    }
    asm volatile("" ::: "memory");
    // no __syncthreads: each wave reads only its own tiles; same-wave LDS order guaranteed

    // ---- stage 2a: zh = bf16(p + (v-mu)*rs*g + b) via transposed LDS read ----
    bf16x8 zh[4];
    #pragma unroll
    for (int s = 0; s < 4; ++s) {
        int byte = (n * 256 + s * 64 + q * 16) ^ ((n & 7) << 4);
        bf16x8 ph = *(const bf16x8*)(pB + byte);
        bf16x8 vh = *(const bf16x8*)(vB + byte);
        const float* gp = attn_g + s * 32 + q * 8;
        const float* bp = attn_b + s * 32 + q * 8;
        f32x4 g0 = *(const f32x4*)gp, g1 = *(const f32x4*)(gp + 4);
        f32x4 b0 = *(const f32x4*)bp, b1 = *(const f32x4*)(bp + 4);
        float z[8];
        #pragma unroll
        for (int j = 0; j < 4; ++j) {
            z[j]     = bf2f(ph[j])     + (bf2f(vh[j])     - mu_n) * rs_n * g0[j] + b0[j];
            z[j + 4] = bf2f(ph[j + 4]) + (bf2f(vh[j + 4]) - mu_n) * rs_n * g1[j] + b1[j];
        }
        FragU f;
        f.u[0] = pack_hi(z[0], z[1]); f.u[1] = pack_hi(z[2], z[3]);
        f.u[2] = pack_hi(z[4], z[5]); f.u[3] = pack_hi(z[6], z[7]);
        zh[s] = f.v;
    }
    asm volatile("" ::: "memory");           // p/v tiles consumed; region reused as fp32 F-tile

    // ---- stage 2b: F = silu(z@Wl + bl), two halves, silu spills fp32 to LDS; LN after ----
    float* fz = (float*)pB;                  // 8 KB = [16][128] fp32, overlays p+v regions
    f32x4 t1 = {0,0,0,0}, t2 = {0,0,0,0};
    #pragma unroll 1
    for (int h = 0; h < 2; ++h) {
        f32x4 F[4];
        #pragma unroll
        for (int t = 0; t < 4; ++t) {
            float bv = lin_b[(h * 4 + t) * 16 + n];
            F[t] = (f32x4){bv, bv, bv, bv};
        }
        #pragma unroll
        for (int s = 0; s < 4; ++s)
            #pragma unroll
            for (int t = 0; t < 4; ++t) {
                int col = (h * 4 + t) * 16 + n;
                bf16x8 wlh = *(const bf16x8*)(wbf + WB_WL + col * 128 + s * 32 + q * 8);
                F[t] = MFMA(zh[s], wlh, F[t]);
            }
        #pragma unroll
        for (int t = 0; t < 4; ++t)
            #pragma unroll
            for (int r = 0; r < 4; ++r) {
                float v = F[t][r];
                v = v / (1.f + __expf(-v));
                t1[r] += v; t2[r] += v * v;
                fz[(q * 4 + r) * 128 + (h * 4 + t) * 16 + n] = v;
            }
    }
    asm volatile("" ::: "memory");
    #pragma unroll
    for (int r = 0; r < 4; ++r) {
        float a1 = t1[r], a2 = t2[r];
        a1 += __shfl_xor(a1, 1); a2 += __shfl_xor(a2, 1);
        a1 += __shfl_xor(a1, 2); a2 += __shfl_xor(a2, 2);
        a1 += __shfl_xor(a1, 4); a2 += __shfl_xor(a2, 4);
        a1 += __shfl_xor(a1, 8); a2 += __shfl_xor(a2, 8);
        t1[r] = a1; t2[r] = a2;
    }
    #pragma unroll
    for (int t = 0; t < 8; ++t) {
        float g = ln_g[t * 16 + n];
        float bb = ln_b[t * 16 + n];
        #pragma unroll
        for (int r = 0; r < 4; ++r) {
            float mu = t1[r] * (1.f / 128.f);
            float var = t2[r] * (1.f / 128.f) - mu * mu;
            float rs = rsqrtf(var + EPS_LN);
            float v = fz[(q * 4 + r) * 128 + t * 16 + n];
            size_t row = (size_t)blockIdx.x * 64 + w * 16 + q * 4 + r;
            out[row * 128 + t * 16 + n] = (v - mu) * rs * g + bb;
        }
    }
}

extern "C" void kernel_launch(void* const* d_in, const int* in_sizes, int n_in,
                              void* d_out, int out_size, void* d_ws, size_t ws_size,
                              hipStream_t stream) {
    const float* x       = (const float*)d_in[0];
    const int*   erows   = (const int*)d_in[1];
    const int*   ecols   = (const int*)d_in[2];
    const float* evals   = (const float*)d_in[3];
    const float* sage_W  = (const float*)d_in[4];
    const float* sage_b  = (const float*)d_in[5];
    const float* sage_aW = (const float*)d_in[6];
    const float* key_W   = (const float*)d_in[7];
    const float* query_W = (const float*)d_in[8];
    const float* value_W = (const float*)d_in[9];
    const float* attn_g  = (const float*)d_in[10];
    const float* attn_b  = (const float*)d_in[11];
    const float* lin_W   = (const float*)d_in[12];
    const float* lin_b   = (const float*)d_in[13];
    const float* ln_g    = (const float*)d_in[14];
    const float* ln_b    = (const float*)d_in[15];
    float* out = (float*)d_out;

    int*   wsi = (int*)d_ws;
    float* wsf = (float*)d_ws;
    int*   cnt      = wsi + OFF_CNT;
    int*   row_ptr  = wsi + OFF_ROWPTR;
    int*   row_ofs  = wsi + OFF_ROWOFS;
    int*   csr_cols = wsi + OFF_CCOLS;
    float* csr_vals = wsf + OFF_CVALS;
    short* wbf      = (short*)(wsf + OFF_WBF);
    short* Abf      = (short*)(wsf + OFF_A);
    short* Bbf      = (short*)(wsf + OFF_B);
    short* Xbf      = (short*)(wsf + OFF_XBF);
    int*   bsum     = (int*)(wsf + OFF_A);     // scan scratch aliases A (dead until spmm1)
    int*   bofs     = bsum + 64;

    // CSR build + weight prep + x cast (every call; ws is re-poisoned before timed launches)
    hipMemsetAsync(cnt, 0, NN * sizeof(int), stream);
    k_hist<<<(EE + 255) / 256, 256, 0, stream>>>(erows, cnt);
    k_prep<<<(WB_LOGICAL + 255) / 256, 256, 0, stream>>>(sage_W, sage_aW, value_W, lin_W,
                                                         key_W, query_W, wbf);
    k_xcast<<<NN * 16 / 256, 256, 0, stream>>>(x, Xbf);
    k_scan1<<<40, 1024, 0, stream>>>(cnt, row_ptr, bsum);
    k_scan2<<<1, 64, 0, stream>>>(bsum, bofs);
    k_scan3<<<40, 1024, 0, stream>>>(bofs, row_ptr, row_ofs);
    k_scatter<<<(EE + 255) / 256, 256, 0, stream>>>(erows, ecols, evals, row_ofs, csr_cols, csr_vals);

    // A = spmm(x_bf16); B = spmm(A)   (node-major [N][L][D] bf16 in/out, 2 rows/wave)
    k_spmm<<<NN / 8, 256, 0, stream>>>(Xbf, row_ptr, csr_cols, csr_vals, Abf);
    k_spmm<<<NN / 8, 256, 0, stream>>>(Abf, row_ptr, csr_cols, csr_vals, Bbf);

    // fused dense stage (t-halved phases, fp32 F-tile in LDS for final LN)
    k_dense<<<ROWS / 64, 256, 0, stream>>>(x, Abf, Bbf, wbf, sage_b, attn_g, attn_b,
                                           lin_b, ln_g, ln_b, out);
}

// Round 6
// 503.278 us; speedup vs baseline: 1.0928x; 1.0928x over previous
//
#include <hip/hip_runtime.h>
#include <math.h>

#define LL 4
#define NN 40000
#define DD 128
#define EE 320000
#define ROWS (LL*NN)         // 160000
#define ND (NN*DD)           // 5120000
#define EPS_LN 1e-5f

typedef __attribute__((ext_vector_type(8))) short bf16x8;
typedef __attribute__((ext_vector_type(4))) short s16x4;
typedef __attribute__((ext_vector_type(4))) float f32x4;

// ---------------- workspace layout (units of 4 bytes) ----------------
#define OFF_CNT      0                         // NN ints
#define OFF_ROWPTR   40000                     // NN+1
#define OFF_ROWOFS   80004                     // NN
#define OFF_CCOLS    120004                    // EE
#define OFF_CVALS    440004                    // EE
#define OFF_WBF      760004                    // bf16 hi/lo weights (139264 shorts)
#define OFF_A        829636                    // bf16 A [N][L][D]: ROWS*DD shorts
#define OFF_B        (OFF_A + ROWS*DD/2)       // bf16 B [N][L][D]
#define OFF_XBF      (OFF_B + ROWS*DD/2)       // bf16 x [N][L][D] for spmm pass 1
// scan scratch aliases the A region (dead until spmm1, which runs after scan3)

// weight sub-offsets in SHORTS within WBF region, FRAGMENT-MAJOR:
// big matrices: frag f = t*4+s (f<32), each frag = 512 shorts laid out (q*16+n)*8+j
// so a wave's load is base + lane*8 -> one contiguous 1KB coalesced access.
// hi block (16384) then lo block (16384) per matrix. K/Q: frag f = s (4 frags),
// 2048 hi then 2048 lo.
#define WB_W0  0        // sage_W^T
#define WB_W1  32768    // sage_agg_W^T
#define WB_WV  65536    // value_W^T
#define WB_WL  98304    // lin_W^T
#define WB_K   131072   // key_W^T
#define WB_Q   135168   // query_W^T
#define WB_LO_BIG 16384
#define WB_LO_KQ  2048
#define WB_LOGICAL 69632

__device__ __forceinline__ unsigned fu(float f) { union { float f; unsigned u; } v; v.f = f; return v.u; }
__device__ __forceinline__ float uf(unsigned u) { union { unsigned u; float f; } v; v.u = u; return v.f; }

__device__ __forceinline__ short f2bf(float f) {           // RNE
    unsigned u = fu(f);
    unsigned r = u + 0x7fffu + ((u >> 16) & 1u);
    return (short)(r >> 16);
}
__device__ __forceinline__ float bf2f(short h) { return uf(((unsigned)(unsigned short)h) << 16); }
__device__ __forceinline__ void splitbf(float v, short& h, short& l) {  // prep only
    h = f2bf(v);
    l = f2bf(v - bf2f(h));
}

// truncation pack: two floats -> one VGPR of 2 bf16 (lo short = a, hi short = b)
__device__ __forceinline__ unsigned pack_hi(float a, float b) {
    return (fu(a) >> 16) | (fu(b) & 0xffff0000u);
}
// truncation residual
__device__ __forceinline__ float resid(float a) {
    return a - uf(fu(a) & 0xffff0000u);
}

union FragU { bf16x8 v; unsigned u[4]; };

// ---------------- CSR build ----------------
__global__ void k_hist(const int* __restrict__ rows, int* __restrict__ cnt) {
    int e = blockIdx.x * 256 + threadIdx.x;
    if (e < EE) atomicAdd(&cnt[rows[e]], 1);
}

// hierarchical scan: scan1 (40 blocks local excl-scan) -> scan2 (scan 40 totals) -> scan3 (add offsets)
__global__ __launch_bounds__(1024) void k_scan1(const int* __restrict__ cnt,
                                                int* __restrict__ row_ptr,
                                                int* __restrict__ bsum) {
    __shared__ int wtot[16];
    int tid = threadIdx.x, lane = tid & 63, wid = tid >> 6;
    int i = blockIdx.x * 1024 + tid;
    int v = (i < NN) ? cnt[i] : 0;
    int incl = v;
    #pragma unroll
    for (int off = 1; off < 64; off <<= 1) {
        int t = __shfl_up(incl, off);
        if (lane >= off) incl += t;
    }
    if (lane == 63) wtot[wid] = incl;
    __syncthreads();
    if (wid == 0) {
        int wv = (lane < 16) ? wtot[lane] : 0;
        #pragma unroll
        for (int off = 1; off < 16; off <<= 1) {
            int t = __shfl_up(wv, off);
            if (lane >= off) wv += t;
        }
        if (lane < 16) wtot[lane] = wv;
    }
    __syncthreads();
    int excl = ((wid > 0) ? wtot[wid - 1] : 0) + incl - v;
    if (i < NN) row_ptr[i] = excl;            // local exclusive; global offset added in scan3
    if (tid == 0) bsum[blockIdx.x] = wtot[15];
}

__global__ void k_scan2(const int* __restrict__ bsum, int* __restrict__ bofs) {
    int lane = threadIdx.x;                   // 64 threads, 1 block
    int v = (lane < 40) ? bsum[lane] : 0;
    int incl = v;
    #pragma unroll
    for (int off = 1; off < 64; off <<= 1) {
        int t = __shfl_up(incl, off);
        if (lane >= off) incl += t;
    }
    if (lane < 40) bofs[lane] = incl - v;
    if (lane == 39) bofs[40] = incl;          // grand total
}

__global__ __launch_bounds__(1024) void k_scan3(const int* __restrict__ bofs,
                                                int* __restrict__ row_ptr,
                                                int* __restrict__ row_ofs) {
    int i = blockIdx.x * 1024 + threadIdx.x;
    int add = bofs[blockIdx.x];
    if (i < NN) {
        int v = row_ptr[i] + add;
        row_ptr[i] = v;
        row_ofs[i] = v;
    }
    if (i == NN) row_ptr[NN] = bofs[40];
}

__global__ void k_scatter(const int* __restrict__ rows, const int* __restrict__ cols,
                          const float* __restrict__ vals, int* __restrict__ row_ofs,
                          int* __restrict__ csr_cols, float* __restrict__ csr_vals) {
    int e = blockIdx.x * 256 + threadIdx.x;
    if (e < EE) {
        int r = rows[e];
        int p = atomicAdd(&row_ofs[r], 1);
        csr_cols[p] = cols[e];
        csr_vals[p] = vals[e];
    }
}

// ---------------- x [L][N][D] fp32 -> Xbf [N][L][D] bf16 (node-major for spmm gathers) ----------------
__global__ __launch_bounds__(256) void k_xcast(const float* __restrict__ x, short* __restrict__ o) {
    int t = blockIdx.x * 256 + threadIdx.x;   // 2500 blocks: t in [0, 640000)
    int n = t >> 4;
    int d8 = (t & 15) * 8;
    #pragma unroll
    for (int l = 0; l < LL; ++l) {
        const float* xp = x + (size_t)l * ND + (size_t)n * 128 + d8;
        f32x4 a = *(const f32x4*)xp;
        f32x4 b = *(const f32x4*)(xp + 4);
        bf16x8 r;
        #pragma unroll
        for (int j = 0; j < 4; ++j) { r[j] = f2bf(a[j]); r[j + 4] = f2bf(b[j]); }
        *(bf16x8*)(o + (size_t)n * 512 + l * 128 + d8) = r;
    }
}

// ---------------- SpMM node-major, 2 rows per wave ----------------
// [N][L][D] bf16: each edge's gather is one contiguous 1 KB wave access. Two
// consecutive rows per wave = two independent gather chains interleaved (4+4 deep)
// for 2x memory-level parallelism when latency-bound. 4 waves/block => 8 rows/block.
__global__ __launch_bounds__(256) void k_spmm(const short* __restrict__ in,
                                              const int* __restrict__ row_ptr,
                                              const int* __restrict__ ccols,
                                              const float* __restrict__ cvals,
                                              short* __restrict__ out) {
    int wid = blockIdx.x * 4 + (threadIdx.x >> 6);
    int rA = wid * 2;                        // rows rA, rA+1
    int lane = threadIdx.x & 63;
    const short* inl = in + lane * 8;
    float accA[8] = {0.f,0.f,0.f,0.f,0.f,0.f,0.f,0.f};
    float accB[8] = {0.f,0.f,0.f,0.f,0.f,0.f,0.f,0.f};
    int a0 = row_ptr[rA], a1 = row_ptr[rA + 1], b1 = row_ptr[rA + 2];
    int b0 = a1;
    // joint loop: 4 gathers per row in flight (8 total)
    while (a0 + 4 <= a1 && b0 + 4 <= b1) {
        int ca[4], cb[4]; float va[4], vb[4]; bf16x8 xa[4], xb[4];
        #pragma unroll
        for (int j = 0; j < 4; ++j) {
            ca[j] = ccols[a0 + j]; va[j] = cvals[a0 + j];
            cb[j] = ccols[b0 + j]; vb[j] = cvals[b0 + j];
        }
        #pragma unroll
        for (int j = 0; j < 4; ++j) {
            xa[j] = *(const bf16x8*)(inl + (size_t)ca[j] * 512);
            xb[j] = *(const bf16x8*)(inl + (size_t)cb[j] * 512);
        }
        #pragma unroll
        for (int j = 0; j < 4; ++j)
            #pragma unroll
            for (int k = 0; k < 8; ++k) {
                accA[k] += va[j] * bf2f(xa[j][k]);
                accB[k] += vb[j] * bf2f(xb[j][k]);
            }
        a0 += 4; b0 += 4;
    }
    // per-row tails (4-deep then scalar)
    #pragma unroll 1
    for (int pass = 0; pass < 2; ++pass) {
        int e = pass ? b0 : a0, e1 = pass ? b1 : a1;
        float* acc = pass ? accB : accA;
        for (; e + 4 <= e1; e += 4) {
            int cc[4]; float vv[4]; bf16x8 xv[4];
            #pragma unroll
            for (int j = 0; j < 4; ++j) { cc[j] = ccols[e + j]; vv[j] = cvals[e + j]; }
            #pragma unroll
            for (int j = 0; j < 4; ++j) xv[j] = *(const bf16x8*)(inl + (size_t)cc[j] * 512);
            #pragma unroll
            for (int j = 0; j < 4; ++j)
                #pragma unroll
                for (int k = 0; k < 8; ++k) acc[k] += vv[j] * bf2f(xv[j][k]);
        }
        for (; e < e1; ++e) {
            int c = ccols[e];
            float v = cvals[e];
            bf16x8 xv = *(const bf16x8*)(inl + (size_t)c * 512);
            #pragma unroll
            for (int k = 0; k < 8; ++k) acc[k] += v * bf2f(xv[k]);
        }
    }
    bf16x8 oA, oB;
    #pragma unroll
    for (int k = 0; k < 8; ++k) { oA[k] = f2bf(accA[k]); oB[k] = f2bf(accB[k]); }
    *(bf16x8*)(out + (size_t)rA * 512 + lane * 8) = oA;
    *(bf16x8*)(out + (size_t)(rA + 1) * 512 + lane * 8) = oB;
}

// ---------------- weight prep: fp32 [k][n] -> bf16 hi/lo FRAGMENT-MAJOR ----------------
// dest (big): o[m*32768 + (t*4+s)*512 + (q*16+n)*8 + j] = M[(s*32+q*8+j)*128 + t*16+n]
// dest (K/Q): o[WB_K + sel*4096 + s*512 + (q*16+n)*8 + j] = M[(s*32+q*8+j)*16 + n]
// so k_dense loads any fragment as base + lane*8: one coalesced 1KB wave access.
__global__ void k_prep(const float* __restrict__ W0, const float* __restrict__ W1,
                       const float* __restrict__ Wv, const float* __restrict__ Wl,
                       const float* __restrict__ Kw, const float* __restrict__ Qw,
                       short* __restrict__ o) {
    int t = blockIdx.x * 256 + threadIdx.x;
    if (t >= WB_LOGICAL) return;
    float v;
    int hi_idx, lo_idx;
    if (t < 65536) {
        int m = t >> 14, idx = t & 16383;
        int col = idx >> 7, kk = idx & 127;
        const float* M = (m == 0) ? W0 : (m == 1) ? W1 : (m == 2) ? Wv : Wl;
        v = M[kk * 128 + col];
        int tt = col >> 4, nn = col & 15;
        int s = kk >> 5, q = (kk >> 3) & 3, j = kk & 7;
        int fm = (tt * 4 + s) * 512 + (q * 16 + nn) * 8 + j;
        hi_idx = m * 32768 + fm;
        lo_idx = hi_idx + WB_LO_BIG;
    } else {
        int t2 = t - 65536;
        int sel = t2 >> 11;
        int idx = t2 & 2047;
        int nn = idx >> 7, kk = idx & 127;
        const float* M = sel ? Qw : Kw;
        v = M[kk * 16 + nn];
        int s = kk >> 5, q = (kk >> 3) & 3, j = kk & 7;
        int fm = s * 512 + (q * 16 + nn) * 8 + j;
        hi_idx = WB_K + sel * 4096 + fm;
        lo_idx = hi_idx + WB_LO_KQ;
    }
    short h, l;
    splitbf(v, h, l);
    o[hi_idx] = h;
    o[lo_idx] = l;
}

// ============ fused dense stage (r2 monolithic structure + fragment-major weights) ============
// 2500 blocks x 256 (4 waves); wave w owns rows blk*64 + w*16 .. +16 (full 128 cols).
// MFMA 16x16x32 bf16 (m89-verified):
//   A-frag: lane holds row m=lane&15, k=(lane>>4)*8+j   B-frag: col n=lane&15, same k
//   C/D:    col = lane&15, row = (lane>>4)*4 + reg
// Round-5 lesson: dense throughput is ~independent of occupancy (11% ~= 31%); the
// cost is per-wave issue/latency. So: best-measured monolithic structure (r2) +
// fragment-major weights (every weight load = sgpr-base + lane*16B: coalesced 8-line
// access, zero per-load VALU address math, vs 16-way divergent before).
// x stays fp32 split-bf16 on the qk path: wts is sign-critical (LN(V*wts) is
// scale-invariant but sign-flips for near-zero wts; need eps ~1e-5 there).
#define MFMA(a, b, c) __builtin_amdgcn_mfma_f32_16x16x32_bf16(a, b, c, 0, 0, 0)

__global__ __launch_bounds__(256) void k_dense(
    const float* __restrict__ x, const short* __restrict__ A, const short* __restrict__ B,
    const short* __restrict__ wbf,
    const float* __restrict__ sage_b, const float* __restrict__ attn_g,
    const float* __restrict__ attn_b, const float* __restrict__ lin_b,
    const float* __restrict__ ln_g, const float* __restrict__ ln_b,
    float* __restrict__ out)
{
    __shared__ short zs[4][16 * 128];        // per-wave 16x128 bf16 Z tile, XOR-swizzled
    const int tid = threadIdx.x;
    const int w = tid >> 6;
    const int lane = tid & 63;
    const int n = lane & 15;
    const int q = lane >> 4;
    const int rowA = blockIdx.x * 64 + w * 16 + n;     // = l*NN + node (blocks never straddle layers)
    const int l = rowA / NN;
    const int node = rowA - l * NN;
    char* zb = (char*)&zs[0][0] + w * 4096;
    const short* wl8 = wbf + lane * 8;       // fragment-major: all weight loads = wl8 + frag ofs

    bf16x8 xh[4], ah[4], ch[4];              // persistent frags
    f32x4 kx = {0,0,0,0}, qx = {0,0,0,0};
    f32x4 ka = {0,0,0,0}, qa = {0,0,0,0};
    f32x4 kb = {0,0,0,0}, qb = {0,0,0,0};

    {
        const float* xp = x + (size_t)rowA * 128 + q * 8;
        const short* ap = A + (size_t)node * 512 + l * 128 + q * 8;   // [N][L][D]
        const short* bp = B + (size_t)node * 512 + l * 128 + q * 8;
        #pragma unroll
        for (int s = 0; s < 4; ++s) {
            f32x4 x0 = *(const f32x4*)(xp + s * 32);
            f32x4 x1 = *(const f32x4*)(xp + s * 32 + 4);
            bf16x8 av = *(const bf16x8*)(ap + s * 32);
            bf16x8 bv = *(const bf16x8*)(bp + s * 32);

            f32x4 c0, c1;
            #pragma unroll
            for (int j = 0; j < 4; ++j) {
                c0[j] = x0[j] + 0.5f * bf2f(av[j])     + 0.25f * bf2f(bv[j]);
                c1[j] = x1[j] + 0.5f * bf2f(av[j + 4]) + 0.25f * bf2f(bv[j + 4]);
            }

            FragU fxh, fxl, fch;
            #pragma unroll
            for (int i = 0; i < 2; ++i) {
                fxh.u[i]     = pack_hi(x0[2*i], x0[2*i+1]);
                fxh.u[i + 2] = pack_hi(x1[2*i], x1[2*i+1]);
                fxl.u[i]     = pack_hi(resid(x0[2*i]), resid(x0[2*i+1]));
                fxl.u[i + 2] = pack_hi(resid(x1[2*i]), resid(x1[2*i+1]));
                fch.u[i]     = pack_hi(c0[2*i], c0[2*i+1]);
                fch.u[i + 2] = pack_hi(c1[2*i], c1[2*i+1]);
            }
            xh[s] = fxh.v; ah[s] = av; ch[s] = fch.v;

            bf16x8 bkh = *(const bf16x8*)(wl8 + WB_K + s * 512);
            bf16x8 bkl = *(const bf16x8*)(wl8 + WB_K + WB_LO_KQ + s * 512);
            bf16x8 bqh = *(const bf16x8*)(wl8 + WB_Q + s * 512);
            bf16x8 bql = *(const bf16x8*)(wl8 + WB_Q + WB_LO_KQ + s * 512);
            // x path: split product hi.hi + lo.hi + hi.lo
            kx = MFMA(fxh.v, bkh, kx); kx = MFMA(fxl.v, bkh, kx); kx = MFMA(fxh.v, bkl, kx);
            qx = MFMA(fxh.v, bqh, qx); qx = MFMA(fxl.v, bqh, qx); qx = MFMA(fxh.v, bql, qx);
            // A/B paths: hi-only (terms carry 0.25 / 0.0625 weight)
            ka = MFMA(av, bkh, ka); qa = MFMA(av, bqh, qa);
            kb = MFMA(bv, bkh, kb); qb = MFMA(bv, bqh, qb);
        }
    }

    // wts = mean(kx*qx) + 0.25*mean(ka*qa) + 0.0625*mean(kb*qb)   (mean over 16 cols)
    f32x4 wts;
    #pragma unroll
    for (int r = 0; r < 4; ++r) {
        float p = kx[r] * qx[r] + 0.25f * (ka[r] * qa[r]) + 0.0625f * (kb[r] * qb[r]);
        p += __shfl_xor(p, 1);
        p += __shfl_xor(p, 2);
        p += __shfl_xor(p, 4);
        p += __shfl_xor(p, 8);
        wts[r] = p * (1.f / 16.f);
    }

    // ---- SAGE: S = silu(x@W0 + b + A@W1)   (hi-only) ----
    f32x4 S[8];
    #pragma unroll
    for (int t = 0; t < 8; ++t) {
        float bv = sage_b[t * 16 + n];
        S[t] = (f32x4){bv, bv, bv, bv};
    }
    #pragma unroll
    for (int s = 0; s < 4; ++s) {
        #pragma unroll
        for (int t = 0; t < 8; ++t) {
            bf16x8 w0h = *(const bf16x8*)(wl8 + WB_W0 + (t * 4 + s) * 512);
            S[t] = MFMA(xh[s], w0h, S[t]);
            bf16x8 w1h = *(const bf16x8*)(wl8 + WB_W1 + (t * 4 + s) * 512);
            S[t] = MFMA(ah[s], w1h, S[t]);
        }
    }
    #pragma unroll
    for (int t = 0; t < 8; ++t)
        #pragma unroll
        for (int r = 0; r < 4; ++r) {
            float v = S[t][r];
            S[t][r] = v / (1.f + __expf(-v));
        }

    // ---- value: V = (c @ Wv) * wts, LN -> attn; Z = S + attn -> LDS (bf16, swizzled) ----
    f32x4 V[8];
    #pragma unroll
    for (int t = 0; t < 8; ++t) V[t] = (f32x4){0.f, 0.f, 0.f, 0.f};
    #pragma unroll
    for (int s = 0; s < 4; ++s)
        #pragma unroll
        for (int t = 0; t < 8; ++t) {
            bf16x8 wvh = *(const bf16x8*)(wl8 + WB_WV + (t * 4 + s) * 512);
            V[t] = MFMA(ch[s], wvh, V[t]);
        }
    f32x4 s1 = {0,0,0,0}, s2 = {0,0,0,0};
    #pragma unroll
    for (int t = 0; t < 8; ++t)
        #pragma unroll
        for (int r = 0; r < 4; ++r) {
            float v = V[t][r] * wts[r];
            V[t][r] = v;
            s1[r] += v; s2[r] += v * v;
        }
    #pragma unroll
    for (int r = 0; r < 4; ++r) {
        float a1 = s1[r], a2 = s2[r];
        a1 += __shfl_xor(a1, 1); a2 += __shfl_xor(a2, 1);
        a1 += __shfl_xor(a1, 2); a2 += __shfl_xor(a2, 2);
        a1 += __shfl_xor(a1, 4); a2 += __shfl_xor(a2, 4);
        a1 += __shfl_xor(a1, 8); a2 += __shfl_xor(a2, 8);
        s1[r] = a1; s2[r] = a2;
    }
    #pragma unroll
    for (int t = 0; t < 8; ++t) {
        float g = attn_g[t * 16 + n];
        float bb = attn_b[t * 16 + n];
        #pragma unroll
        for (int r = 0; r < 4; ++r) {
            float mu = s1[r] * (1.f / 128.f);
            float var = s2[r] * (1.f / 128.f) - mu * mu;
            float rs = rsqrtf(var + EPS_LN);
            float zval = S[t][r] + (V[t][r] - mu) * rs * g + bb;
            int row = q * 4 + r;
            int byte = (row * 256 + (t * 16 + n) * 2) ^ ((row & 7) << 4);
            *(short*)(zb + byte) = f2bf(zval);
        }
    }
    // no __syncthreads: each wave reads only its own tile; same-wave LDS order is guaranteed

    // ---- stage 2: out = LN(silu(Z@Wl + bl))  (hi-only), Z tile from LDS transpose ----
    bf16x8 zh[4];
    #pragma unroll
    for (int s = 0; s < 4; ++s) {
        int byte = (n * 256 + s * 64 + q * 16) ^ ((n & 7) << 4);
        zh[s] = *(const bf16x8*)(zb + byte);
    }
    f32x4 F[8];
    #pragma unroll
    for (int t = 0; t < 8; ++t) {
        float bv = lin_b[t * 16 + n];
        F[t] = (f32x4){bv, bv, bv, bv};
    }
    #pragma unroll
    for (int s = 0; s < 4; ++s)
        #pragma unroll
        for (int t = 0; t < 8; ++t) {
            bf16x8 wlh = *(const bf16x8*)(wl8 + WB_WL + (t * 4 + s) * 512);
            F[t] = MFMA(zh[s], wlh, F[t]);
        }
    f32x4 t1 = {0,0,0,0}, t2 = {0,0,0,0};
    #pragma unroll
    for (int t = 0; t < 8; ++t)
        #pragma unroll
        for (int r = 0; r < 4; ++r) {
            float v = F[t][r];
            v = v / (1.f + __expf(-v));
            F[t][r] = v;
            t1[r] += v; t2[r] += v * v;
        }
    #pragma unroll
    for (int r = 0; r < 4; ++r) {
        float a1 = t1[r], a2 = t2[r];
        a1 += __shfl_xor(a1, 1); a2 += __shfl_xor(a2, 1);
        a1 += __shfl_xor(a1, 2); a2 += __shfl_xor(a2, 2);
        a1 += __shfl_xor(a1, 4); a2 += __shfl_xor(a2, 4);
        a1 += __shfl_xor(a1, 8); a2 += __shfl_xor(a2, 8);
        t1[r] = a1; t2[r] = a2;
    }
    #pragma unroll
    for (int t = 0; t < 8; ++t) {
        float g = ln_g[t * 16 + n];
        float bb = ln_b[t * 16 + n];
        #pragma unroll
        for (int r = 0; r < 4; ++r) {
            float mu = t1[r] * (1.f / 128.f);
            float var = t2[r] * (1.f / 128.f) - mu * mu;
            float rs = rsqrtf(var + EPS_LN);
            size_t row = (size_t)blockIdx.x * 64 + w * 16 + q * 4 + r;
            out[row * 128 + t * 16 + n] = (F[t][r] - mu) * rs * g + bb;
        }
    }
}

extern "C" void kernel_launch(void* const* d_in, const int* in_sizes, int n_in,
                              void* d_out, int out_size, void* d_ws, size_t ws_size,
                              hipStream_t stream) {
    const float* x       = (const float*)d_in[0];
    const int*   erows   = (const int*)d_in[1];
    const int*   ecols   = (const int*)d_in[2];
    const float* evals   = (const float*)d_in[3];
    const float* sage_W  = (const float*)d_in[4];
    const float* sage_b  = (const float*)d_in[5];
    const float* sage_aW = (const float*)d_in[6];
    const float* key_W   = (const float*)d_in[7];
    const float* query_W = (const float*)d_in[8];
    const float* value_W = (const float*)d_in[9];
    const float* attn_g  = (const float*)d_in[10];
    const float* attn_b  = (const float*)d_in[11];
    const float* lin_W   = (const float*)d_in[12];
    const float* lin_b   = (const float*)d_in[13];
    const float* ln_g    = (const float*)d_in[14];
    const float* ln_b    = (const float*)d_in[15];
    float* out = (float*)d_out;

    int*   wsi = (int*)d_ws;
    float* wsf = (float*)d_ws;
    int*   cnt      = wsi + OFF_CNT;
    int*   row_ptr  = wsi + OFF_ROWPTR;
    int*   row_ofs  = wsi + OFF_ROWOFS;
    int*   csr_cols = wsi + OFF_CCOLS;
    float* csr_vals = wsf + OFF_CVALS;
    short* wbf      = (short*)(wsf + OFF_WBF);
    short* Abf      = (short*)(wsf + OFF_A);
    short* Bbf      = (short*)(wsf + OFF_B);
    short* Xbf      = (short*)(wsf + OFF_XBF);
    int*   bsum     = (int*)(wsf + OFF_A);     // scan scratch aliases A (dead until spmm1)
    int*   bofs     = bsum + 64;

    // CSR build + weight prep + x cast (every call; ws is re-poisoned before timed launches)
    hipMemsetAsync(cnt, 0, NN * sizeof(int), stream);
    k_hist<<<(EE + 255) / 256, 256, 0, stream>>>(erows, cnt);
    k_prep<<<(WB_LOGICAL + 255) / 256, 256, 0, stream>>>(sage_W, sage_aW, value_W, lin_W,
                                                         key_W, query_W, wbf);
    k_xcast<<<NN * 16 / 256, 256, 0, stream>>>(x, Xbf);
    k_scan1<<<40, 1024, 0, stream>>>(cnt, row_ptr, bsum);
    k_scan2<<<1, 64, 0, stream>>>(bsum, bofs);
    k_scan3<<<40, 1024, 0, stream>>>(bofs, row_ptr, row_ofs);
    k_scatter<<<(EE + 255) / 256, 256, 0, stream>>>(erows, ecols, evals, row_ofs, csr_cols, csr_vals);

    // A = spmm(x_bf16); B = spmm(A)   (node-major [N][L][D] bf16 in/out, 2 rows/wave)
    k_spmm<<<NN / 8, 256, 0, stream>>>(Xbf, row_ptr, csr_cols, csr_vals, Abf);
    k_spmm<<<NN / 8, 256, 0, stream>>>(Abf, row_ptr, csr_cols, csr_vals, Bbf);

    // fused dense stage (monolithic r2 structure + fragment-major coalesced weights)
    k_dense<<<ROWS / 64, 256, 0, stream>>>(x, Abf, Bbf, wbf, sage_b, attn_g, attn_b,
                                           lin_b, ln_g, ln_b, out);
}